// Round 3
// baseline (629.320 us; speedup 1.0000x reference)
//
#include <hip/hip_runtime.h>
#include <hip/hip_bf16.h>

typedef unsigned short u16;
typedef short bf16x8 __attribute__((ext_vector_type(8)));
typedef float f32x4 __attribute__((ext_vector_type(4)));

#define NB 2
#define NS 2048
#define ND 1536
#define NH 8
#define NCQK 128
#define NCV 192
#define NBS 4096
#define NPAD 1408

__device__ __forceinline__ float bf2f(u16 u) {
  unsigned v = ((unsigned)u) << 16;
  return __builtin_bit_cast(float, v);
}
__device__ __forceinline__ u16 f2bf(float f) {
  unsigned u = __builtin_bit_cast(unsigned, f);
  u += 0x7fffu + ((u >> 16) & 1u);
  return (u16)(u >> 16);
}
__device__ __forceinline__ f32x4 mfma16(bf16x8 a, bf16x8 b, f32x4 c) {
  return __builtin_amdgcn_mfma_f32_16x16x32_bf16(a, b, c, 0, 0, 0);
}

// ---------------- transpose+cast: out[n][k] = bf16(in[k][n]), in fp32 [K][N] ----------------
__global__ void transpose_k(const float* __restrict__ in, u16* __restrict__ out,
                            int K, int N) {
  __shared__ float t[64][65];
  const int n0 = blockIdx.x * 64, k0 = blockIdx.y * 64;
  const int tid = threadIdx.x;
  const int rl = tid >> 4, cl = (tid & 15) * 4;
  for (int p = 0; p < 4; p++) {
    int k = rl + p * 16;
    float4 v = *(const float4*)(in + (size_t)(k0 + k) * N + n0 + cl);
    t[k][cl] = v.x; t[k][cl + 1] = v.y; t[k][cl + 2] = v.z; t[k][cl + 3] = v.w;
  }
  __syncthreads();
  const int rn = tid >> 3, ck = (tid & 7) * 8;
  for (int p = 0; p < 2; p++) {
    int n = rn + p * 32;
    u16 tmp[8];
    for (int j = 0; j < 8; j++) tmp[j] = f2bf(t[ck + j][n]);
    *(uint4*)(out + (size_t)(n0 + n) * K + k0 + ck) = *(uint4*)tmp;
  }
}

// ---------------- rmsnorm of x (fp32) -> h (bf16) ----------------
__global__ void rmsnorm_in_k(const float* __restrict__ x, const float* __restrict__ scale,
                             u16* __restrict__ h) {
  __shared__ float sbuf[4];
  const int row = blockIdx.x, tid = threadIdx.x;
  const float* xr = x + (size_t)row * ND;
  float v[6]; float ss = 0.f;
  for (int i = 0; i < 6; i++) { v[i] = xr[tid + i * 256]; ss += v[i] * v[i]; }
  for (int o = 32; o; o >>= 1) ss += __shfl_xor(ss, o);
  if ((tid & 63) == 0) sbuf[tid >> 6] = ss;
  __syncthreads();
  ss = sbuf[0] + sbuf[1] + sbuf[2] + sbuf[3];
  const float inv = rsqrtf(ss * (1.f / ND) + 1e-6f);
  u16* hr = h + (size_t)row * ND;
  for (int i = 0; i < 6; i++) {
    int c = tid + i * 256;
    hr[c] = f2bf(v[i] * inv * scale[c]);
  }
}

// ---------------- C[M,N] = A[M,K]bf16 @ Bt[N,K]bf16^T ; fp32 or bf16 out ----------------
template <bool F32OUT>
__global__ __launch_bounds__(256, 2)
void gemm_nt(const u16* __restrict__ A, const u16* __restrict__ Bt,
             float* __restrict__ Cf, u16* __restrict__ Cb, int M, int N, int K) {
  __shared__ __align__(16) u16 As[128 * 64];
  __shared__ __align__(16) u16 Bs[128 * 64];
  const int tid = threadIdx.x;
  const int wave = tid >> 6, lane = tid & 63, quad = lane >> 4, l16 = lane & 15;
  const int m0 = blockIdx.y * 128, n0 = blockIdx.x * 128;
  const int mrb = (wave & 1) * 4, nrb = (wave >> 1) * 4;
  f32x4 acc[4][4] = {};
  for (int k0 = 0; k0 < K; k0 += 64) {
    if (k0) __syncthreads();
    for (int i = 0; i < 4; i++) {
      int g = wave * 4 + i;
      int rb = g >> 1, kh = g & 1;
      int row = rb * 16 + l16, kc = kh * 4 + quad;
      uint4 va = *(const uint4*)(A + (size_t)(m0 + row) * K + k0 + kc * 8);
      uint4 vb = *(const uint4*)(Bt + (size_t)(n0 + row) * K + k0 + kc * 8);
      *(uint4*)&As[(rb * 8 + kh * 4) * 128 + lane * 8] = va;
      *(uint4*)&Bs[(rb * 8 + kh * 4) * 128 + lane * 8] = vb;
    }
    __syncthreads();
    for (int kk = 0; kk < 2; kk++) {
      bf16x8 af[4], bfr[4];
      for (int f = 0; f < 4; f++)
        af[f] = *(const bf16x8*)&As[(((mrb + f) * 8 + kk * 4 + quad) * 16 + l16) * 8];
      for (int f = 0; f < 4; f++)
        bfr[f] = *(const bf16x8*)&Bs[(((nrb + f) * 8 + kk * 4 + quad) * 16 + l16) * 8];
      for (int mf = 0; mf < 4; mf++)
        for (int nf = 0; nf < 4; nf++)
          acc[mf][nf] = mfma16(af[mf], bfr[nf], acc[mf][nf]);
    }
  }
  for (int mf = 0; mf < 4; mf++)
    for (int nf = 0; nf < 4; nf++)
      for (int r = 0; r < 4; r++) {
        int m = m0 + (wave & 1) * 64 + mf * 16 + quad * 4 + r;
        int n = n0 + (wave >> 1) * 64 + nf * 16 + l16;
        if (F32OUT) Cf[(size_t)m * N + n] = acc[mf][nf][r];
        else        Cb[(size_t)m * N + n] = f2bf(acc[mf][nf][r]);
      }
}

// ---------------- layernorm + rope on qkv rows (fp32 in, bf16 out) ----------------
__global__ void ln_rope_k(const float* __restrict__ qkv,
                          const float* __restrict__ qs, const float* __restrict__ qo,
                          const float* __restrict__ ks, const float* __restrict__ ko,
                          const float* __restrict__ vs, const float* __restrict__ vo,
                          u16* __restrict__ Qg, u16* __restrict__ Kg, u16* __restrict__ Vg) {
  const int row = blockIdx.x;
  const int b = row >> 11, s = row & (NS - 1);
  const int wave = threadIdx.x >> 6, lane = threadIdx.x & 63;
  const float* base = qkv + (size_t)row * NPAD;
  const float gsp = __expf(logf(8129.f) * ((float)lane * (1.f / 63.f)));
  const float invf = 1.f / ((float)lane + gsp);
  float sn, cs;
  sincosf((float)s * invf, &sn, &cs);

  for (int hh = 0; hh < 2; hh++) {
    const int h = wave * 2 + hh;
    const float* p = base + h * NCQK;
    float x0 = p[lane * 2], x1 = p[lane * 2 + 1];
    float s1 = x0 + x1, s2 = x0 * x0 + x1 * x1;
    for (int o = 32; o; o >>= 1) { s1 += __shfl_xor(s1, o); s2 += __shfl_xor(s2, o); }
    float mean = s1 * (1.f / NCQK);
    float inv = rsqrtf(s2 * (1.f / NCQK) - mean * mean + 1e-5f);
    float y0 = (x0 - mean) * inv * qs[lane * 2] + qo[lane * 2];
    float y1 = (x1 - mean) * inv * qs[lane * 2 + 1] + qo[lane * 2 + 1];
    u16* dst = Qg + (size_t)row * (NH * NCQK) + h * NCQK + lane * 2;
    dst[0] = f2bf(y0 * cs - y1 * sn);
    dst[1] = f2bf(y1 * cs + y0 * sn);
  }
  if (wave == 0) {
    const float* p = base + NH * NCQK;
    float x0 = p[lane * 2], x1 = p[lane * 2 + 1];
    float s1 = x0 + x1, s2 = x0 * x0 + x1 * x1;
    for (int o = 32; o; o >>= 1) { s1 += __shfl_xor(s1, o); s2 += __shfl_xor(s2, o); }
    float mean = s1 * (1.f / NCQK);
    float inv = rsqrtf(s2 * (1.f / NCQK) - mean * mean + 1e-5f);
    float y0 = (x0 - mean) * inv * ks[lane * 2] + ko[lane * 2];
    float y1 = (x1 - mean) * inv * ks[lane * 2 + 1] + ko[lane * 2 + 1];
    u16* dst = Kg + (size_t)row * NCQK + lane * 2;
    dst[0] = f2bf(y0 * cs - y1 * sn);
    dst[1] = f2bf(y1 * cs + y0 * sn);
  }
  if (wave == 1) {
    const float* p = base + NH * NCQK + NCQK;
    float x[3]; float s1 = 0.f, s2 = 0.f;
    for (int i = 0; i < 3; i++) { x[i] = p[lane + i * 64]; s1 += x[i]; s2 += x[i] * x[i]; }
    for (int o = 32; o; o >>= 1) { s1 += __shfl_xor(s1, o); s2 += __shfl_xor(s2, o); }
    float mean = s1 * (1.f / NCV);
    float inv = rsqrtf(s2 * (1.f / NCV) - mean * mean + 1e-5f);
    for (int i = 0; i < 3; i++) {
      int c = lane + i * 64;
      float y = (x[i] - mean) * inv * vs[c] + vo[c];
      Vg[(size_t)(b * NCV + c) * NS + s] = f2bf(y);
    }
  }
}

// ---------------- fused MQA attention (softcap -> no running max needed) ----------------
__global__ __launch_bounds__(256, 2)
void attn_k(const u16* __restrict__ Qg, const u16* __restrict__ Kg,
            const u16* __restrict__ Vg, const float* __restrict__ bias,
            u16* __restrict__ Y) {
  __shared__ __align__(16) u16 Qs[64 * 128];
  __shared__ __align__(16) u16 Ks[64 * 128];
  __shared__ __align__(16) u16 Vs[192 * 64];
  __shared__ __align__(16) u16 Ps[64 * 64];
  const int tid = threadIdx.x;
  const int wave = tid >> 6, lane = tid & 63, quad = lane >> 4, l16 = lane & 15;
  const int s0 = blockIdx.x * 64;
  const int h = blockIdx.y, b = blockIdx.z;

  for (int i = 0; i < 4; i++) {
    int g = wave * 4 + i;
    int qb = g >> 2, kcg = g & 3;
    int q = qb * 16 + l16, kc = kcg * 4 + quad;
    uint4 v = *(const uint4*)(Qg + ((size_t)((b * NS + s0 + q) * NH + h)) * NCQK + kc * 8);
    *(uint4*)&Qs[(qb * 16 + kcg * 4) * 128 + lane * 8] = v;
  }

  f32x4 oacc[12] = {};
  float lsum[4] = {0.f, 0.f, 0.f, 0.f};
  bf16x8 qa[4];
  const float* brow = bias + ((size_t)(b * NH + h) * NS + s0 + wave * 16) * NS;

  for (int kt = 0; kt < NS / 64; kt++) {
    const int key0 = kt * 64;
    if (kt) __syncthreads();
    for (int i = 0; i < 4; i++) {
      int g = wave * 4 + i;
      int kb = g >> 2, kcg = g & 3;
      int ky = kb * 16 + l16, kc = kcg * 4 + quad;
      uint4 v = *(const uint4*)(Kg + (size_t)(b * NS + key0 + ky) * NCQK + kc * 8);
      *(uint4*)&Ks[(kb * 16 + kcg * 4) * 128 + lane * 8] = v;
    }
    for (int i = 0; i < 6; i++) {
      int g = wave * 6 + i;
      int cb = g >> 1, kh = g & 1;
      int cv = cb * 16 + l16, kc = kh * 4 + quad;
      uint4 v = *(const uint4*)(Vg + (size_t)(b * NCV + cv) * NS + key0 + kc * 8);
      *(uint4*)&Vs[(cb * 8 + kh * 4) * 128 + lane * 8] = v;
    }
    __syncthreads();
    if (kt == 0)
      for (int kk = 0; kk < 4; kk++)
        qa[kk] = *(const bf16x8*)&Qs[((wave * 16 + kk * 4 + quad) * 16 + l16) * 8];

    f32x4 sacc[4] = {};
    for (int kk = 0; kk < 4; kk++)
      for (int nb = 0; nb < 4; nb++) {
        bf16x8 kf = *(const bf16x8*)&Ks[((nb * 16 + kk * 4 + quad) * 16 + l16) * 8];
        sacc[nb] = mfma16(qa[kk], kf, sacc[nb]);
      }

    for (int nb = 0; nb < 4; nb++) {
      const int key_l = nb * 16 + l16;
      const float* bp = brow + key0 + key_l;
      for (int r = 0; r < 4; r++) {
        const int qrow = quad * 4 + r;
        float sv = sacc[nb][r] * 0.08838834764831845f + bp[(size_t)qrow * NS];
        float e2 = __expf(sv * 0.4f);
        float cap = 5.f - 10.f / (e2 + 1.f);   // 5*tanh(sv/5)
        u16 pb = f2bf(__expf(cap));
        lsum[r] += bf2f(pb);
        Ps[((wave * 8 + (key_l >> 3)) * 16 + qrow) * 8 + (key_l & 7)] = pb;
      }
    }

    for (int kk = 0; kk < 2; kk++) {
      bf16x8 pa = *(const bf16x8*)&Ps[((wave * 8 + kk * 4 + quad) * 16 + l16) * 8];
      for (int nb = 0; nb < 12; nb++) {
        bf16x8 vf = *(const bf16x8*)&Vs[((nb * 8 + kk * 4 + quad) * 16 + l16) * 8];
        oacc[nb] = mfma16(pa, vf, oacc[nb]);
      }
    }
  }

  for (int r = 0; r < 4; r++)
    for (int o = 1; o < 16; o <<= 1) lsum[r] += __shfl_xor(lsum[r], o);
  for (int r = 0; r < 4; r++) {
    const float inv = 1.f / lsum[r];
    const int m = s0 + wave * 16 + quad * 4 + r;
    u16* yr = Y + (size_t)(b * NS + m) * ND + h * NCV;
    for (int nb = 0; nb < 12; nb++) yr[nb * 16 + l16] = f2bf(oacc[nb][r] * inv);
  }
}

// ---------------- +bo, rmsnorm, write fp32 out ----------------
__global__ void final_k(const u16* __restrict__ yo, const float* __restrict__ bo,
                        const float* __restrict__ scale, float* __restrict__ out) {
  __shared__ float sbuf[4];
  const int row = blockIdx.x, tid = threadIdx.x;
  const u16* yr = yo + (size_t)row * ND;
  float v[6]; float ss = 0.f;
  for (int i = 0; i < 6; i++) {
    int c = tid + i * 256;
    v[i] = bf2f(yr[c]) + bo[c];
    ss += v[i] * v[i];
  }
  for (int o = 32; o; o >>= 1) ss += __shfl_xor(ss, o);
  if ((tid & 63) == 0) sbuf[tid >> 6] = ss;
  __syncthreads();
  ss = sbuf[0] + sbuf[1] + sbuf[2] + sbuf[3];
  const float inv = rsqrtf(ss * (1.f / ND) + 1e-6f);
  float* orow = out + (size_t)row * ND;
  for (int i = 0; i < 6; i++) {
    int c = tid + i * 256;
    orow[c] = v[i] * inv * scale[c];
  }
}

extern "C" void kernel_launch(void* const* d_in, const int* in_sizes, int n_in,
                              void* d_out, int out_size, void* d_ws, size_t ws_size,
                              hipStream_t stream) {
  const float* x    = (const float*)d_in[0];
  const float* bias = (const float*)d_in[1];
  const float* rin  = (const float*)d_in[2];
  const float* wq   = (const float*)d_in[3];
  const float* wk   = (const float*)d_in[4];
  const float* wv   = (const float*)d_in[5];
  const float* qsc  = (const float*)d_in[6];
  const float* qof  = (const float*)d_in[7];
  const float* ksc  = (const float*)d_in[8];
  const float* kof  = (const float*)d_in[9];
  const float* vsc  = (const float*)d_in[10];
  const float* vof  = (const float*)d_in[11];
  const float* wo   = (const float*)d_in[12];
  const float* bo   = (const float*)d_in[13];
  const float* rout = (const float*)d_in[14];

  char* ws = (char*)d_ws;
  size_t off = 0;
  auto alloc = [&](size_t bytes) -> void* {
    void* p = ws + off;
    off += (bytes + 255) & ~(size_t)255;
    return p;
  };
  u16*   h    = (u16*)alloc((size_t)NBS * ND * 2);
  u16*   wtq  = (u16*)alloc((size_t)NPAD * ND * 2);
  u16*   wto  = (u16*)alloc((size_t)ND * ND * 2);
  float* qkv  = (float*)alloc((size_t)NBS * NPAD * 4);
  u16*   Qb   = (u16*)alloc((size_t)NBS * NH * NCQK * 2);
  u16*   Kb   = (u16*)alloc((size_t)NBS * NCQK * 2);
  u16*   Vtb  = (u16*)alloc((size_t)NB * NCV * NS * 2);
  u16*   Ybf  = (u16*)alloc((size_t)NBS * ND * 2);
  u16*   Yob  = (u16*)alloc((size_t)NBS * ND * 2);

  transpose_k<<<dim3(16, 24), 256, 0, stream>>>(wq, wtq, ND, 1024);
  transpose_k<<<dim3(2, 24), 256, 0, stream>>>(wk, wtq + (size_t)1024 * ND, ND, 128);
  transpose_k<<<dim3(3, 24), 256, 0, stream>>>(wv, wtq + (size_t)1152 * ND, ND, 192);
  transpose_k<<<dim3(24, 24), 256, 0, stream>>>(wo, wto, ND, ND);
  rmsnorm_in_k<<<NBS, 256, 0, stream>>>(x, rin, h);
  gemm_nt<true><<<dim3(NPAD / 128, NBS / 128), 256, 0, stream>>>(h, wtq, qkv, nullptr, NBS, NPAD, ND);
  ln_rope_k<<<NBS, 256, 0, stream>>>(qkv, qsc, qof, ksc, kof, vsc, vof, Qb, Kb, Vtb);
  attn_k<<<dim3(NS / 64, NH, NB), 256, 0, stream>>>(Qb, Kb, Vtb, bias, Ybf);
  gemm_nt<false><<<dim3(ND / 128, NBS / 128), 256, 0, stream>>>(Ybf, wto, nullptr, Yob, NBS, ND, ND);
  final_k<<<NBS, 256, 0, stream>>>(Yob, bo, rout, (float*)d_out);
}

// Round 4
// 592.880 us; speedup vs baseline: 1.0615x; 1.0615x over previous
//
#include <hip/hip_runtime.h>
#include <hip/hip_bf16.h>

typedef unsigned short u16;
typedef short bf16x8 __attribute__((ext_vector_type(8)));
typedef float f32x4 __attribute__((ext_vector_type(4)));

#define NB 2
#define NS 2048
#define ND 1536
#define NH 8
#define NCQK 128
#define NCV 192
#define NBS 4096
#define NPAD 1408

__device__ __forceinline__ float bf2f(u16 u) {
  unsigned v = ((unsigned)u) << 16;
  return __builtin_bit_cast(float, v);
}
__device__ __forceinline__ u16 f2bf(float f) {
  unsigned u = __builtin_bit_cast(unsigned, f);
  u += 0x7fffu + ((u >> 16) & 1u);
  return (u16)(u >> 16);
}
__device__ __forceinline__ void glds16(const u16* g, u16* l) {
  __builtin_amdgcn_global_load_lds(
      (const __attribute__((address_space(1))) void*)g,
      (__attribute__((address_space(3))) void*)l, 16, 0, 0);
}
__device__ __forceinline__ f32x4 mfma16(bf16x8 a, bf16x8 b, f32x4 c) {
  return __builtin_amdgcn_mfma_f32_16x16x32_bf16(a, b, c, 0, 0, 0);
}

// ---------------- transpose+cast: out[n][k] = bf16(in[k][n]), in fp32 [K][N] ----------------
__global__ void transpose_k(const float* __restrict__ in, u16* __restrict__ out,
                            int K, int N) {
  __shared__ float t[64][65];
  const int n0 = blockIdx.x * 64, k0 = blockIdx.y * 64;
  const int tid = threadIdx.x;
  const int rl = tid >> 4, cl = (tid & 15) * 4;
  for (int p = 0; p < 4; p++) {
    int k = rl + p * 16;
    float4 v = *(const float4*)(in + (size_t)(k0 + k) * N + n0 + cl);
    t[k][cl] = v.x; t[k][cl + 1] = v.y; t[k][cl + 2] = v.z; t[k][cl + 3] = v.w;
  }
  __syncthreads();
  const int rn = tid >> 3, ck = (tid & 7) * 8;
  for (int p = 0; p < 2; p++) {
    int n = rn + p * 32;
    u16 tmp[8];
    for (int j = 0; j < 8; j++) tmp[j] = f2bf(t[ck + j][n]);
    *(uint4*)(out + (size_t)(n0 + n) * K + k0 + ck) = *(uint4*)tmp;
  }
}

// ---------------- rmsnorm of x (fp32) -> h (bf16) ----------------
__global__ void rmsnorm_in_k(const float* __restrict__ x, const float* __restrict__ scale,
                             u16* __restrict__ h) {
  __shared__ float sbuf[4];
  const int row = blockIdx.x, tid = threadIdx.x;
  const float* xr = x + (size_t)row * ND;
  float v[6]; float ss = 0.f;
  for (int i = 0; i < 6; i++) { v[i] = xr[tid + i * 256]; ss += v[i] * v[i]; }
  for (int o = 32; o; o >>= 1) ss += __shfl_xor(ss, o);
  if ((tid & 63) == 0) sbuf[tid >> 6] = ss;
  __syncthreads();
  ss = sbuf[0] + sbuf[1] + sbuf[2] + sbuf[3];
  const float inv = rsqrtf(ss * (1.f / ND) + 1e-6f);
  u16* hr = h + (size_t)row * ND;
  for (int i = 0; i < 6; i++) {
    int c = tid + i * 256;
    hr[c] = f2bf(v[i] * inv * scale[c]);
  }
}

// ---------------- C[M,N] = A[M,K]bf16 @ Bt[N,K]bf16^T ; fp32 or bf16 out ----------------
template <bool F32OUT>
__global__ __launch_bounds__(256, 2)
void gemm_nt(const u16* __restrict__ A, const u16* __restrict__ Bt,
             float* __restrict__ Cf, u16* __restrict__ Cb, int M, int N, int K) {
  __shared__ __align__(16) u16 As[128 * 64];
  __shared__ __align__(16) u16 Bs[128 * 64];
  const int tid = threadIdx.x;
  const int wave = tid >> 6, lane = tid & 63, quad = lane >> 4, l16 = lane & 15;
  const int m0 = blockIdx.y * 128, n0 = blockIdx.x * 128;
  const int mrb = (wave & 1) * 4, nrb = (wave >> 1) * 4;
  f32x4 acc[4][4] = {};
  for (int k0 = 0; k0 < K; k0 += 64) {
    if (k0) __syncthreads();
    for (int i = 0; i < 4; i++) {
      int g = wave * 4 + i;
      int rb = g >> 1, kh = g & 1;
      int row = rb * 16 + l16, kc = kh * 4 + quad;
      glds16(A + (size_t)(m0 + row) * K + k0 + kc * 8, &As[(rb * 8 + kh * 4) * 128]);
      glds16(Bt + (size_t)(n0 + row) * K + k0 + kc * 8, &Bs[(rb * 8 + kh * 4) * 128]);
    }
    __syncthreads();
    for (int kk = 0; kk < 2; kk++) {
      bf16x8 af[4], bfr[4];
      for (int f = 0; f < 4; f++)
        af[f] = *(const bf16x8*)&As[(((mrb + f) * 8 + kk * 4 + quad) * 16 + l16) * 8];
      for (int f = 0; f < 4; f++)
        bfr[f] = *(const bf16x8*)&Bs[(((nrb + f) * 8 + kk * 4 + quad) * 16 + l16) * 8];
      for (int mf = 0; mf < 4; mf++)
        for (int nf = 0; nf < 4; nf++)
          acc[mf][nf] = mfma16(af[mf], bfr[nf], acc[mf][nf]);
    }
  }
  for (int mf = 0; mf < 4; mf++)
    for (int nf = 0; nf < 4; nf++)
      for (int r = 0; r < 4; r++) {
        int m = m0 + (wave & 1) * 64 + mf * 16 + quad * 4 + r;
        int n = n0 + (wave >> 1) * 64 + nf * 16 + l16;
        if (F32OUT) Cf[(size_t)m * N + n] = acc[mf][nf][r];
        else        Cb[(size_t)m * N + n] = f2bf(acc[mf][nf][r]);
      }
}

// ---------------- layernorm + rope on qkv rows (fp32 in, bf16 out) ----------------
__global__ void ln_rope_k(const float* __restrict__ qkv,
                          const float* __restrict__ qs, const float* __restrict__ qo,
                          const float* __restrict__ ks, const float* __restrict__ ko,
                          const float* __restrict__ vs, const float* __restrict__ vo,
                          u16* __restrict__ Qg, u16* __restrict__ Kg, u16* __restrict__ Vg) {
  const int row = blockIdx.x;
  const int b = row >> 11, s = row & (NS - 1);
  const int wave = threadIdx.x >> 6, lane = threadIdx.x & 63;
  const float* base = qkv + (size_t)row * NPAD;
  const float gsp = __expf(logf(8129.f) * ((float)lane * (1.f / 63.f)));
  const float invf = 1.f / ((float)lane + gsp);
  float sn, cs;
  sincosf((float)s * invf, &sn, &cs);

  for (int hh = 0; hh < 2; hh++) {
    const int h = wave * 2 + hh;
    const float* p = base + h * NCQK;
    float x0 = p[lane * 2], x1 = p[lane * 2 + 1];
    float s1 = x0 + x1, s2 = x0 * x0 + x1 * x1;
    for (int o = 32; o; o >>= 1) { s1 += __shfl_xor(s1, o); s2 += __shfl_xor(s2, o); }
    float mean = s1 * (1.f / NCQK);
    float inv = rsqrtf(s2 * (1.f / NCQK) - mean * mean + 1e-5f);
    float y0 = (x0 - mean) * inv * qs[lane * 2] + qo[lane * 2];
    float y1 = (x1 - mean) * inv * qs[lane * 2 + 1] + qo[lane * 2 + 1];
    u16* dst = Qg + (size_t)row * (NH * NCQK) + h * NCQK + lane * 2;
    dst[0] = f2bf(y0 * cs - y1 * sn);
    dst[1] = f2bf(y1 * cs + y0 * sn);
  }
  if (wave == 0) {
    const float* p = base + NH * NCQK;
    float x0 = p[lane * 2], x1 = p[lane * 2 + 1];
    float s1 = x0 + x1, s2 = x0 * x0 + x1 * x1;
    for (int o = 32; o; o >>= 1) { s1 += __shfl_xor(s1, o); s2 += __shfl_xor(s2, o); }
    float mean = s1 * (1.f / NCQK);
    float inv = rsqrtf(s2 * (1.f / NCQK) - mean * mean + 1e-5f);
    float y0 = (x0 - mean) * inv * ks[lane * 2] + ko[lane * 2];
    float y1 = (x1 - mean) * inv * ks[lane * 2 + 1] + ko[lane * 2 + 1];
    u16* dst = Kg + (size_t)row * NCQK + lane * 2;
    dst[0] = f2bf(y0 * cs - y1 * sn);
    dst[1] = f2bf(y1 * cs + y0 * sn);
  }
  if (wave == 1) {
    const float* p = base + NH * NCQK + NCQK;
    float x[3]; float s1 = 0.f, s2 = 0.f;
    for (int i = 0; i < 3; i++) { x[i] = p[lane + i * 64]; s1 += x[i]; s2 += x[i] * x[i]; }
    for (int o = 32; o; o >>= 1) { s1 += __shfl_xor(s1, o); s2 += __shfl_xor(s2, o); }
    float mean = s1 * (1.f / NCV);
    float inv = rsqrtf(s2 * (1.f / NCV) - mean * mean + 1e-5f);
    for (int i = 0; i < 3; i++) {
      int c = lane + i * 64;
      float y = (x[i] - mean) * inv * vs[c] + vo[c];
      Vg[(size_t)(b * NCV + c) * NS + s] = f2bf(y);
    }
  }
}

// ---------------- fused MQA attention (softcap -> no running max needed) ----------------
__global__ __launch_bounds__(256, 2)
void attn_k(const u16* __restrict__ Qg, const u16* __restrict__ Kg,
            const u16* __restrict__ Vg, const float* __restrict__ bias,
            u16* __restrict__ Y) {
  __shared__ __align__(16) u16 Qs[64 * 128];
  __shared__ __align__(16) u16 Ks[64 * 128];
  __shared__ __align__(16) u16 Vs[192 * 64];
  __shared__ __align__(16) u16 Ps[64 * 64];
  const int tid = threadIdx.x;
  const int wave = tid >> 6, lane = tid & 63, quad = lane >> 4, l16 = lane & 15;
  const int s0 = blockIdx.x * 64;
  const int h = blockIdx.y, b = blockIdx.z;

  const u16* Kbase = Kg + (size_t)(b * NS) * NCQK;
  const u16* Vbase = Vg + (size_t)(b * NCV) * NS;
  const float* brow = bias + ((size_t)(b * NH + h) * NS + s0 + wave * 16) * NS;

  // stage Q + first K/V tile
  for (int i = 0; i < 4; i++) {
    glds16(Qg + ((size_t)((b * NS + s0 + wave * 16 + l16) * NH + h)) * NCQK + (i * 4 + quad) * 8,
           &Qs[(wave * 16 + i * 4) * 128]);
    glds16(Kbase + (size_t)(wave * 16 + l16) * NCQK + (i * 4 + quad) * 8,
           &Ks[(wave * 16 + i * 4) * 128]);
  }
  for (int i = 0; i < 6; i++) {
    int g = wave * 6 + i;
    int cb = g >> 1, kh = g & 1;
    glds16(Vbase + (size_t)(cb * 16 + l16) * NS + (kh * 4 + quad) * 8,
           &Vs[(cb * 8 + kh * 4) * 128]);
  }
  // prefetch bias tile 0 into registers
  float breg[16];
  for (int nb = 0; nb < 4; nb++)
    for (int r = 0; r < 4; r++)
      breg[nb * 4 + r] = brow[(size_t)(quad * 4 + r) * NS + nb * 16 + l16];
  __syncthreads();

  bf16x8 qa[4];
  for (int kk = 0; kk < 4; kk++)
    qa[kk] = *(const bf16x8*)&Qs[((wave * 16 + kk * 4 + quad) * 16 + l16) * 8];

  f32x4 oacc[12] = {};
  float lsum[4] = {0.f, 0.f, 0.f, 0.f};

  for (int kt = 0; kt < NS / 64; kt++) {
    // QK^T
    f32x4 sacc[4] = {};
    for (int kk = 0; kk < 4; kk++)
      for (int nb = 0; nb < 4; nb++) {
        bf16x8 kf = *(const bf16x8*)&Ks[((nb * 16 + kk * 4 + quad) * 16 + l16) * 8];
        sacc[nb] = mfma16(qa[kk], kf, sacc[nb]);
      }

    // softcap + exp, P tile to LDS (bias already in registers)
    for (int nb = 0; nb < 4; nb++) {
      const int key_l = nb * 16 + l16;
      for (int r = 0; r < 4; r++) {
        const int qrow = quad * 4 + r;
        float sv = sacc[nb][r] * 0.08838834764831845f + breg[nb * 4 + r];
        float e2 = __expf(sv * 0.4f);
        float cap = 5.f - 10.f / (e2 + 1.f);   // 5*tanh(sv/5)
        u16 pb = f2bf(__expf(cap));
        lsum[r] += bf2f(pb);
        Ps[((wave * 8 + (key_l >> 3)) * 16 + qrow) * 8 + (key_l & 7)] = pb;
      }
    }

    // PV
    for (int kk = 0; kk < 2; kk++) {
      bf16x8 pa = *(const bf16x8*)&Ps[((wave * 8 + kk * 4 + quad) * 16 + l16) * 8];
      for (int nb = 0; nb < 12; nb++) {
        bf16x8 vf = *(const bf16x8*)&Vs[((nb * 8 + kk * 4 + quad) * 16 + l16) * 8];
        oacc[nb] = mfma16(pa, vf, oacc[nb]);
      }
    }

    // stage next K/V tile (+ prefetch its bias) behind the barriers
    if (kt + 1 < NS / 64) {
      const int key0 = (kt + 1) * 64;
      for (int nb = 0; nb < 4; nb++)
        for (int r = 0; r < 4; r++)
          breg[nb * 4 + r] = brow[(size_t)(quad * 4 + r) * NS + key0 + nb * 16 + l16];
      __syncthreads();
      for (int i = 0; i < 4; i++)
        glds16(Kbase + (size_t)(key0 + wave * 16 + l16) * NCQK + (i * 4 + quad) * 8,
               &Ks[(wave * 16 + i * 4) * 128]);
      for (int i = 0; i < 6; i++) {
        int g = wave * 6 + i;
        int cb = g >> 1, kh = g & 1;
        glds16(Vbase + (size_t)(cb * 16 + l16) * NS + key0 + (kh * 4 + quad) * 8,
               &Vs[(cb * 8 + kh * 4) * 128]);
      }
      __syncthreads();
    }
  }

  for (int r = 0; r < 4; r++)
    for (int o = 1; o < 16; o <<= 1) lsum[r] += __shfl_xor(lsum[r], o);
  for (int r = 0; r < 4; r++) {
    const float inv = 1.f / lsum[r];
    const int m = s0 + wave * 16 + quad * 4 + r;
    u16* yr = Y + (size_t)(b * NS + m) * ND + h * NCV;
    for (int nb = 0; nb < 12; nb++) yr[nb * 16 + l16] = f2bf(oacc[nb][r] * inv);
  }
}

// ---------------- +bo, rmsnorm, write fp32 out ----------------
__global__ void final_k(const u16* __restrict__ yo, const float* __restrict__ bo,
                        const float* __restrict__ scale, float* __restrict__ out) {
  __shared__ float sbuf[4];
  const int row = blockIdx.x, tid = threadIdx.x;
  const u16* yr = yo + (size_t)row * ND;
  float v[6]; float ss = 0.f;
  for (int i = 0; i < 6; i++) {
    int c = tid + i * 256;
    v[i] = bf2f(yr[c]) + bo[c];
    ss += v[i] * v[i];
  }
  for (int o = 32; o; o >>= 1) ss += __shfl_xor(ss, o);
  if ((tid & 63) == 0) sbuf[tid >> 6] = ss;
  __syncthreads();
  ss = sbuf[0] + sbuf[1] + sbuf[2] + sbuf[3];
  const float inv = rsqrtf(ss * (1.f / ND) + 1e-6f);
  float* orow = out + (size_t)row * ND;
  for (int i = 0; i < 6; i++) {
    int c = tid + i * 256;
    orow[c] = v[i] * inv * scale[c];
  }
}

extern "C" void kernel_launch(void* const* d_in, const int* in_sizes, int n_in,
                              void* d_out, int out_size, void* d_ws, size_t ws_size,
                              hipStream_t stream) {
  const float* x    = (const float*)d_in[0];
  const float* bias = (const float*)d_in[1];
  const float* rin  = (const float*)d_in[2];
  const float* wq   = (const float*)d_in[3];
  const float* wk   = (const float*)d_in[4];
  const float* wv   = (const float*)d_in[5];
  const float* qsc  = (const float*)d_in[6];
  const float* qof  = (const float*)d_in[7];
  const float* ksc  = (const float*)d_in[8];
  const float* kof  = (const float*)d_in[9];
  const float* vsc  = (const float*)d_in[10];
  const float* vof  = (const float*)d_in[11];
  const float* wo   = (const float*)d_in[12];
  const float* bo   = (const float*)d_in[13];
  const float* rout = (const float*)d_in[14];

  char* ws = (char*)d_ws;
  size_t off = 0;
  auto alloc = [&](size_t bytes) -> void* {
    void* p = ws + off;
    off += (bytes + 255) & ~(size_t)255;
    return p;
  };
  u16*   h    = (u16*)alloc((size_t)NBS * ND * 2);
  u16*   wtq  = (u16*)alloc((size_t)NPAD * ND * 2);
  u16*   wto  = (u16*)alloc((size_t)ND * ND * 2);
  float* qkv  = (float*)alloc((size_t)NBS * NPAD * 4);
  u16*   Qb   = (u16*)alloc((size_t)NBS * NH * NCQK * 2);
  u16*   Kb   = (u16*)alloc((size_t)NBS * NCQK * 2);
  u16*   Vtb  = (u16*)alloc((size_t)NB * NCV * NS * 2);
  u16*   Ybf  = (u16*)alloc((size_t)NBS * ND * 2);
  u16*   Yob  = (u16*)alloc((size_t)NBS * ND * 2);

  transpose_k<<<dim3(16, 24), 256, 0, stream>>>(wq, wtq, ND, 1024);
  transpose_k<<<dim3(2, 24), 256, 0, stream>>>(wk, wtq + (size_t)1024 * ND, ND, 128);
  transpose_k<<<dim3(3, 24), 256, 0, stream>>>(wv, wtq + (size_t)1152 * ND, ND, 192);
  transpose_k<<<dim3(24, 24), 256, 0, stream>>>(wo, wto, ND, ND);
  rmsnorm_in_k<<<NBS, 256, 0, stream>>>(x, rin, h);
  gemm_nt<true><<<dim3(NPAD / 128, NBS / 128), 256, 0, stream>>>(h, wtq, qkv, nullptr, NBS, NPAD, ND);
  ln_rope_k<<<NBS, 256, 0, stream>>>(qkv, qsc, qof, ksc, kof, vsc, vof, Qb, Kb, Vtb);
  attn_k<<<dim3(NS / 64, NH, NB), 256, 0, stream>>>(Qb, Kb, Vtb, bias, Ybf);
  gemm_nt<false><<<dim3(ND / 128, NBS / 128), 256, 0, stream>>>(Ybf, wto, nullptr, Yob, NBS, ND, ND);
  final_k<<<NBS, 256, 0, stream>>>(Yob, bo, rout, (float*)d_out);
}